// Round 3
// baseline (8247.631 us; speedup 1.0000x reference)
//
#include <hip/hip_runtime.h>
#include <stdint.h>

#define BB 128
#define TT 512
#define EE 128
#define HH 256
#define KK 32
#define ASTRD 386    // f64 stride of A-tile rows (384+2 pad)
#define WSTR  388    // f32 stride of W rows: %32==4 spreads banks, 16B aligned
#define MAGIC 0x13572468

// Workspace: hx f32 [2par][2dir][B][H] @0 (512 KB); cnt @512K; flags @516K;
//            em f64 [B][T][K] @2M (16 MB).
#define OFF_CNT (512ull << 10)
#define OFF_FLG (516ull << 10)
#define OFF_EM  (2ull << 20)

// ---------------------------------------------------------------------------
// k_persist: R13/R14 persistent BiLSTM structure (PASSED at 11134us with 256
// threads). R15 change: 512 threads (8 waves, 2 waves/SIMD) with each thread
// computing 2 rows instead of 4. Rationale: at 1 wave/SIMD every f64-FMA
// dependent-issue stall and every lgkmcnt wait is dead SIMD time; measured
// 52k cy/step vs ~6.1k cy/step f64 floor. A second co-resident wave per SIMD
// executes under the other's stalls. Per-output-element f64 accumulation
// ORDER IS UNCHANGED (same 4-wide FMA grouping, same k order), so xg/g/h/c/em
// are BIT-IDENTICAL to the passing round-0 kernel. Emissions + cell stay on
// threads 0-255 exactly as before (wave-uniform guard). MFMA f64 (R14)
// abandoned: fragment layout unverified on gfx950, absmax blew up.
// LDS: Ah 49.4K + Wl 99.3K + Gl 4.2K + Lw 2K = 155 KB -> 1 block/CU.
// ---------------------------------------------------------------------------
__global__ __launch_bounds__(512, 1) void k_persist(
        const int* __restrict__ tok, const float* __restrict__ table,
        const float* __restrict__ Wihf, const float* __restrict__ Whhf,
        const float* __restrict__ bf,
        const float* __restrict__ Wihb, const float* __restrict__ Whhb,
        const float* __restrict__ bb,
        const float* __restrict__ lw,
        float* __restrict__ hx, int* __restrict__ cnt,
        double* __restrict__ em, int* __restrict__ flags) {
    __shared__ __align__(16) double Ah[16 * ASTRD];
    __shared__ __align__(16) float  Wl[64 * WSTR];
    __shared__ float Gl[16 * 66];
    __shared__ float Lw[2 * 256];

    const int tid  = threadIdx.x;
    const int blk  = blockIdx.x;
    const int grp  = blk & 15;
    const int dir  = grp >> 3;
    const int tile = grp & 7;
    const int hsl  = blk >> 4;
    const int b0   = tile * 16;
    const int u0   = hsl * 16;
    int* mycnt = cnt + grp * 64;

    if (blk == 0 && tid == 0) flags[8] = MAGIC;      // liveness

    const float* Wih = dir ? Wihb : Wihf;
    const float* Whh = dir ? Whhb : Whhf;
    const float* bia = dir ? bb : bf;

    // ---- one-time: W slice into LDS (row c = gate*16+unit, stride 388) ----
    for (int idx = tid; idx < 64 * 384; idx += 512) {
        int c = idx / 384;
        int k = idx - c * 384;
        int grow = (c >> 4) * HH + u0 + (c & 15);
        float v = (k < EE) ? Wih[(size_t)grow * EE + k]
                           : Whh[(size_t)grow * HH + (k - EE)];
        Wl[c * WSTR + k] = v;
    }
    if (tid < 512) {
        int i = tid;
        Lw[i] = lw[(size_t)(hsl * 2 + (i >> 8)) * (2 * HH) + dir * HH + (i & 255)];
    }

    // GEMM mapping: lane c = gate col, wave w (0..7) = rows 2w, 2w+1
    const int c = tid & 63;
    const int w = tid >> 6;
    const float* WrowL = Wl + c * WSTR;
    const float bias_c = bia[(c >> 4) * HH + u0 + (c & 15)];

    const int er = tid >> 4, eu = tid & 15;          // cell mapping (tid<256)
    float c_state = 0.f;
    long guard = 0;
    float xgv[2];

    for (int s = 0; s <= TT; ++s) {
        // ---- stage x(t_s) as f64 (h-independent); 512 float4, 1/thread ----
        if (s < TT) {
            const int t = dir ? (TT - 1 - s) : s;
            const int i = tid;
            const int r = i >> 5, e4 = i & 31;
            int tk = tok[(b0 + r) * TT + t];
            float4 v = make_float4(0.f, 0.f, 0.f, 0.f);
            if (tk != 0) v = ((const float4*)(table + (size_t)tk * EE))[e4];
            double2* dst = (double2*)(Ah + r * ASTRD + e4 * 4);
            dst[0] = make_double2((double)v.x, (double)v.y);
            dst[1] = make_double2((double)v.z, (double)v.w);
        }
        __syncthreads();

        // ---- x-phase GEMM (before barrier wait; hides inter-block skew) ----
        if (s < TT) {
            double a0 = 0.0, a1 = 0.0;
            const double* A0 = Ah + (2 * w + 0) * ASTRD;
            const double* A1 = Ah + (2 * w + 1) * ASTRD;
#pragma unroll 4
            for (int k = 0; k < EE; k += 4) {
                float4 wf = *((const float4*)(WrowL + k));
                const double w0 = wf.x, w1 = wf.y, w2 = wf.z, w3 = wf.w;
                double2 q0, q1;
                q0 = *((const double2*)(A0 + k)); q1 = *((const double2*)(A0 + k + 2));
                a0 += q0.x * w0 + q0.y * w1 + q1.x * w2 + q1.y * w3;
                q0 = *((const double2*)(A1 + k)); q1 = *((const double2*)(A1 + k + 2));
                a1 += q0.x * w0 + q0.y * w1 + q1.x * w2 + q1.y * w3;
            }
            xgv[0] = __fadd_rn((float)a0, bias_c);   // f32(Sx)+b
            xgv[1] = __fadd_rn((float)a1, bias_c);
        }

        // ---- wait for h(s-1) (R13 verbatim) ----
        if (s > 0 && tid == 0) {
            const int target = 16 * s;
            while (__hip_atomic_load(mycnt, __ATOMIC_RELAXED,
                                     __HIP_MEMORY_SCOPE_AGENT) < target) {
                __builtin_amdgcn_s_sleep(2);
                if (++guard > 100000000L) {
                    __hip_atomic_store(&flags[10], s, __ATOMIC_RELAXED,
                                       __HIP_MEMORY_SCOPE_AGENT);
                    break;
                }
            }
            __threadfence();                         // acquire
        }
        __syncthreads();

        // ---- stage h(s-1) as f64 (same element ops as round 0) ----
        if (s == 0) {
            for (int i = tid; i < 2048; i += 512) {
                int r = i >> 7, u2 = i & 127;
                *((double2*)(Ah + r * ASTRD + EE + u2 * 2)) = make_double2(0.0, 0.0);
            }
        } else {
            const int rp = (s & 1) ^ 1;
            int i = tid;
#pragma unroll
            for (int rep = 0; rep < 4; ++rep, i += 512) {
                int r = i >> 7, u2 = i & 127;
                const unsigned long long* p = (const unsigned long long*)
                    (hx + ((size_t)((rp * 2 + dir) * BB + b0 + r)) * HH + u2 * 2);
                unsigned long long raw = __hip_atomic_load(
                    p, __ATOMIC_RELAXED, __HIP_MEMORY_SCOPE_AGENT);
                union { unsigned long long u; float f[2]; } cv; cv.u = raw;
                *((double2*)(Ah + r * ASTRD + EE + u2 * 2)) =
                    make_double2((double)cv.f[0], (double)cv.f[1]);
            }
        }
        __syncthreads();

        // ---- emissions partial for step s-1 (threads 0-255, R10 verbatim) ----
        if (s >= 1 && tid < 256) {
            const int d = tid >> 3, sub = tid & 7;
            const int row = d >> 1, kk = d & 1;
            const int t_em = dir ? (TT - s) : (s - 1);
            double p = 0.0;
#pragma unroll
            for (int j = sub * 32; j < sub * 32 + 32; ++j)
                p += Ah[row * ASTRD + EE + j] * (double)Lw[kk * 256 + j];
            p += __shfl_xor(p, 1, 64);
            p += __shfl_xor(p, 2, 64);
            p += __shfl_xor(p, 4, 64);
            if (sub == 0)
                atomicAdd(em + ((size_t)(b0 + row) * TT + t_em) * KK + hsl * 2 + kk, p);
        }
        if (s == TT) break;

        // ---- h-phase GEMM; g = xg + f32(Sh) -> Gl ----
        {
            double a0 = 0.0, a1 = 0.0;
            const double* A0 = Ah + (2 * w + 0) * ASTRD + EE;
            const double* A1 = Ah + (2 * w + 1) * ASTRD + EE;
            const float* WhL = WrowL + EE;
#pragma unroll 4
            for (int k = 0; k < HH; k += 4) {
                float4 wf = *((const float4*)(WhL + k));
                const double w0 = wf.x, w1 = wf.y, w2 = wf.z, w3 = wf.w;
                double2 q0, q1;
                q0 = *((const double2*)(A0 + k)); q1 = *((const double2*)(A0 + k + 2));
                a0 += q0.x * w0 + q0.y * w1 + q1.x * w2 + q1.y * w3;
                q0 = *((const double2*)(A1 + k)); q1 = *((const double2*)(A1 + k + 2));
                a1 += q0.x * w0 + q0.y * w1 + q1.x * w2 + q1.y * w3;
            }
            Gl[(2 * w + 0) * 66 + c] = __fadd_rn(xgv[0], (float)a0);
            Gl[(2 * w + 1) * 66 + c] = __fadd_rn(xgv[1], (float)a1);
        }
        __syncthreads();

        // ---- LSTM cell (f32 lattice, R13 verbatim; threads 0-255) ----
        if (tid < 256) {
            const float gi = Gl[er * 66 +  0 + eu];
            const float gf = Gl[er * 66 + 16 + eu];
            const float gg = Gl[er * 66 + 32 + eu];
            const float go = Gl[er * 66 + 48 + eu];
            const float si = 1.f / (1.f + expf(-gi));
            const float sf = 1.f / (1.f + expf(-gf));
            const float so = 1.f / (1.f + expf(-go));
            const float tg = tanhf(gg);
            const float cnew = __fadd_rn(__fmul_rn(sf, c_state), __fmul_rn(si, tg));
            c_state = cnew;
            const float hval = __fmul_rn(so, tanhf(cnew));
            __hip_atomic_store(
                hx + ((size_t)(((s & 1) * 2 + dir) * BB + b0 + er)) * HH + u0 + eu,
                hval, __ATOMIC_RELAXED, __HIP_MEMORY_SCOPE_AGENT);
        }

        // ---- signal h(s) ready (R13 verbatim) ----
        __syncthreads();     // drains all waves' h stores (vmcnt(0))
        if (tid == 0) {
            __threadfence();                         // release
            __hip_atomic_fetch_add(mycnt, 1, __ATOMIC_RELAXED,
                                   __HIP_MEMORY_SCOPE_AGENT);
        }
    }
}

// ---------------------------------------------------------------------------
// k_viterbi: f32 DP, reference rounding/order (R10/R13, PASSED verbatim).
// ---------------------------------------------------------------------------
__global__ __launch_bounds__(64) void k_viterbi(const double* __restrict__ em,
                                                const float* __restrict__ lb,
                                                const float* __restrict__ startt,
                                                const float* __restrict__ endt,
                                                const float* __restrict__ trans,
                                                int* __restrict__ out) {
    const int b = blockIdx.x;
    const int lane = threadIdx.x;
    const int j = lane & 31, half = lane >> 5;
    __shared__ float trs[32][33];
    __shared__ unsigned char hist[TT][32];
    __shared__ int tags[TT];

    for (int idx = lane; idx < 1024; idx += 64)
        trs[idx >> 5][idx & 31] = trans[idx];
    __syncthreads();

    const float lbj = lb[j];
    const double* emb = em + (size_t)b * TT * KK;
    float score = __fadd_rn(startt[j], __fadd_rn((float)emb[j], lbj));

    for (int t = 1; t < TT; ++t) {
        const float e_cur = __fadd_rn((float)emb[(size_t)t * KK + j], lbj);
        float best = -3.4e38f; int bi = 0;
#pragma unroll
        for (int ii = 0; ii < 16; ++ii) {
            int i = half * 16 + ii;
            float sc_i = __shfl(score, i, 64);
            float c1 = __fadd_rn(sc_i, trs[i][j]);
            float cand = __fadd_rn(c1, e_cur);
            if (cand > best) { best = cand; bi = i; }    // strict > = first max
        }
        float ob = __shfl_xor(best, 32, 64);
        int obi = __shfl_xor(bi, 32, 64);
        if (ob > best || (ob == best && obi < bi)) { best = ob; bi = obi; }
        score = best;
        if (half == 0) hist[t][j] = (unsigned char)bi;
    }

    score = __fadd_rn(score, endt[j]);
    int bj = j; float bs = score;
#pragma unroll
    for (int off = 16; off >= 1; off >>= 1) {
        float os = __shfl_xor(bs, off, 64);
        int oj = __shfl_xor(bj, off, 64);
        if (os > bs || (os == bs && oj < bj)) { bs = os; bj = oj; }
    }
    __syncthreads();
    if (lane == 0) {
        int cur = bj;
        tags[TT - 1] = cur;
        for (int t = TT - 2; t >= 0; --t) { cur = hist[t + 1][cur]; tags[t] = cur; }
    }
    __syncthreads();
    for (int t2 = lane; t2 < TT; t2 += 64) out[b * TT + t2] = tags[t2];
}

// ---------------------------------------------------------------------------
// k_final: failure decode only (healthy runs untouched).
// ---------------------------------------------------------------------------
__global__ __launch_bounds__(64) void k_final(const int* __restrict__ flags,
                                              int* __restrict__ outp) {
    if (threadIdx.x != 0) return;
    if (flags[8] != MAGIC)   outp[0] = 990000;
    else if (flags[10] != 0) outp[0] = 850000 + flags[10] * 64;
}

// ---------------------------------------------------------------------------
extern "C" void kernel_launch(void* const* d_in, const int* in_sizes, int n_in,
                              void* d_out, int out_size, void* d_ws, size_t ws_size,
                              hipStream_t stream) {
    const int*   tok   = (const int*)d_in[0];
    const float* table = (const float*)d_in[3];
    const float* Wihf  = (const float*)d_in[4];
    const float* Whhf  = (const float*)d_in[5];
    const float* bf    = (const float*)d_in[6];
    const float* Wihb  = (const float*)d_in[7];
    const float* Whhb  = (const float*)d_in[8];
    const float* bb    = (const float*)d_in[9];
    const float* lw    = (const float*)d_in[10];
    const float* lb    = (const float*)d_in[11];
    const float* st    = (const float*)d_in[12];
    const float* en    = (const float*)d_in[13];
    const float* tr    = (const float*)d_in[14];

    if (ws_size < (19ull << 20)) return;

    char* ws = (char*)d_ws;
    float*  hx    = (float*)ws;
    int*    cnt   = (int*)(ws + OFF_CNT);
    int*    flags = (int*)(ws + OFF_FLG);
    double* em    = (double*)(ws + OFF_EM);

    hipMemsetAsync(cnt, 0, 8192, stream);            // cnt + flags
    hipMemsetAsync(em, 0, (size_t)BB * TT * KK * 8, stream);
    k_persist<<<256, 512, 0, stream>>>(tok, table, Wihf, Whhf, bf,
                                       Wihb, Whhb, bb, lw, hx, cnt, em, flags);
    k_viterbi<<<BB, 64, 0, stream>>>(em, lb, st, en, tr, (int*)d_out);
    k_final  <<<1, 64, 0, stream>>>(flags, (int*)d_out);
}

// Round 6
// 8168.287 us; speedup vs baseline: 1.0097x; 1.0097x over previous
//
#include <hip/hip_runtime.h>
#include <stdint.h>

#define BB 128
#define TT 512
#define EE 128
#define HH 256
#define KK 32
#define ASTRD 386    // f64 stride of A-tile rows (384+2 pad)
#define WSTR  388    // f32 stride of W rows: %32==4, 16B aligned
#define MAGIC 0x13572468

typedef double f64x4 __attribute__((ext_vector_type(4)));

// Workspace: hx f32 [2par][2dir][B][H] @0 (512 KB); cnt @512K; flags @516K;
//            em f64 [B][T][K] @2M (16 MB).
#define OFF_CNT (512ull << 10)
#define OFF_FLG (516ull << 10)
#define OFF_EM  (2ull << 20)

// ---------------------------------------------------------------------------
// k_persist: R3 structure (PASSED, 8247us) + self-verified f64-MFMA GEMM path.
// R3 analysis: VALUBusy 42%, MfmaUtil 0, 39k cy/step vs 6.1k f64-FMA floor.
// Scalar path is LDS-instr + VALU-issue bound (A re-broadcast per wave: 3072
// wave-instrs/CU/step; W reads 768; 384 cvt/thread). MFMA f64 16x16x4:
//  - MACs move to matrix pipe: 96 MFMA x 64cy = 6144 cy/SIMD/step = the floor
//  - A-frags distributed: 96 ds_read_b64/wave (64 elems each) vs 384 bcasts
//  - B-frags: 96 b32+cvt/thread (4x fewer cvts)
// R1's MFMA failed on UNVERIFIED fragment layout -> this version PROBES the
// layout at runtime (register-only, exact integer-in-f64 checks, __ballot):
//   mode 1: canonical  A[m=l&15][k=l>>4], B[k=l>>4][n=l&15],
//           D: col=l&15, row=4*(l>>4)+r  (matches verified 16x16 f32 family)
//   mode 2: same A/B, D transposed: row=l&15, col=4*(l>>4)+r
//   mode 0: fallback = R3 scalar GEMM verbatim (bit-identical, PASSES)
// Mode folds into precomputed Gl indices + bias regs -> single MFMA body.
// MFMA reads the SAME row-major Ah/Wl as scalar path (bank-checked: ~4-way on
// A b64, off critical path). Staging/sync/em/cell/Viterbi: R3 verbatim.
// LDS: Ah 49.4K + Wl 99.3K + Gl 4.2K + Lw 2K = 155 KB -> 1 block/CU.
// ---------------------------------------------------------------------------
__global__ __launch_bounds__(512, 1) void k_persist(
        const int* __restrict__ tok, const float* __restrict__ table,
        const float* __restrict__ Wihf, const float* __restrict__ Whhf,
        const float* __restrict__ bf,
        const float* __restrict__ Wihb, const float* __restrict__ Whhb,
        const float* __restrict__ bb,
        const float* __restrict__ lw,
        float* __restrict__ hx, int* __restrict__ cnt,
        double* __restrict__ em, int* __restrict__ flags) {
    __shared__ __align__(16) double Ah[16 * ASTRD];
    __shared__ __align__(16) float  Wl[64 * WSTR];
    __shared__ float Gl[16 * 66];
    __shared__ float Lw[2 * 256];

    const int tid  = threadIdx.x;
    const int blk  = blockIdx.x;
    const int grp  = blk & 15;
    const int dir  = grp >> 3;
    const int tile = grp & 7;
    const int hsl  = blk >> 4;
    const int b0   = tile * 16;
    const int u0   = hsl * 16;
    int* mycnt = cnt + grp * 64;

    if (blk == 0 && tid == 0) flags[8] = MAGIC;      // liveness

    const float* Wih = dir ? Wihb : Wihf;
    const float* Whh = dir ? Whhb : Whhf;
    const float* bia = dir ? bb : bf;

    // ---- one-time: W slice into LDS (row c = gate*16+unit, stride 388) ----
    for (int idx = tid; idx < 64 * 384; idx += 512) {
        int c = idx / 384;
        int k = idx - c * 384;
        int grow = (c >> 4) * HH + u0 + (c & 15);
        float v = (k < EE) ? Wih[(size_t)grow * EE + k]
                           : Whh[(size_t)grow * HH + (k - EE)];
        Wl[c * WSTR + k] = v;
    }
    {
        int i = tid;
        Lw[i] = lw[(size_t)(hsl * 2 + (i >> 8)) * (2 * HH) + dir * HH + (i & 255)];
    }

    const int l = tid & 63;
    const int w = tid >> 6;

    // ---- runtime MFMA layout probe (register-only, exact) ----
    int mode = 0;
    {
        f64x4 z; z[0] = 0.0; z[1] = 0.0; z[2] = 0.0; z[3] = 0.0;
        double a1 = (double)(l & 15);                 // A[m][k] = m (canonical)
        double b1 = (l == 0) ? 1.0 : 0.0;             // B[0][0] = 1
        f64x4 d1 = __builtin_amdgcn_mfma_f64_16x16x4f64(a1, b1, z, 0, 0, 0);
        double a2 = (double)(l >> 4);                 // A[m][k] = k
        double b2 = (l == ((3 << 4) | 5)) ? 1.0 : 0.0; // B[3][5] = 1
        f64x4 d2 = __builtin_amdgcn_mfma_f64_16x16x4f64(a2, b2, z, 0, 0, 0);
        bool okC = true, okT = true;
#pragma unroll
        for (int r = 0; r < 4; ++r) {
            const int rowC = 4 * (l >> 4) + r;        // canonical D row
            double e1C = ((l & 15) == 0) ? (double)rowC : 0.0;
            double e2C = ((l & 15) == 5) ? 3.0 : 0.0;
            okC = okC && (d1[r] == e1C) && (d2[r] == e2C);
            double e1T = (rowC == 0) ? (double)(l & 15) : 0.0;  // D transposed
            double e2T = (rowC == 5) ? 3.0 : 0.0;
            okT = okT && (d1[r] == e1T) && (d2[r] == e2T);
        }
        if (__ballot(okC ? 1 : 0) == ~0ull)      mode = 1;
        else if (__ballot(okT ? 1 : 0) == ~0ull) mode = 2;
    }

    // ---- scalar-path mapping (R3 verbatim) ----
    const int c = tid & 63;
    const float* WrowL = Wl + c * WSTR;
    const float bias_c = bia[(c >> 4) * HH + u0 + (c & 15)];

    // ---- MFMA-path mapping (waves 0-3, gate g = w) ----
    const int kq = l >> 4;
    const double* Arow = Ah + (l & 15) * ASTRD;       // A frag: m = l&15
    const float*  Wb   = Wl + (w * 16 + (l & 15)) * WSTR + kq;  // B: n=l&15
    int   glIdx[4];
    float biasv[4];
#pragma unroll
    for (int r = 0; r < 4; ++r) {
        int row_u, col_u;                              // (batch-row, unit)
        if (mode == 2) { row_u = l & 15; col_u = 4 * kq + r; }
        else           { row_u = 4 * kq + r; col_u = l & 15; }
        glIdx[r] = row_u * 66 + w * 16 + col_u;
        biasv[r] = bia[w * HH + u0 + col_u];
    }

    const int er = tid >> 4, eu = tid & 15;          // cell mapping (tid<256)
    float c_state = 0.f;
    long guard = 0;
    float xgv[2];
    float xgm[4];

    for (int s = 0; s <= TT; ++s) {
        // ---- stage x(t_s) as f64 (h-independent); 512 float4, 1/thread ----
        if (s < TT) {
            const int t = dir ? (TT - 1 - s) : s;
            const int i = tid;
            const int r = i >> 5, e4 = i & 31;
            int tk = tok[(b0 + r) * TT + t];
            float4 v = make_float4(0.f, 0.f, 0.f, 0.f);
            if (tk != 0) v = ((const float4*)(table + (size_t)tk * EE))[e4];
            double2* dst = (double2*)(Ah + r * ASTRD + e4 * 4);
            dst[0] = make_double2((double)v.x, (double)v.y);
            dst[1] = make_double2((double)v.z, (double)v.w);
        }
        __syncthreads();

        // ---- x-phase GEMM (before barrier wait; hides inter-block skew) ----
        if (s < TT) {
            if (mode != 0) {
                if (w < 4) {
                    f64x4 ax0; ax0[0]=0.0; ax0[1]=0.0; ax0[2]=0.0; ax0[3]=0.0;
                    f64x4 ax1 = ax0;
#pragma unroll 8
                    for (int kb = 0; kb < 32; kb += 2) {
                        double a0 = Arow[kb * 4 + kq];
                        double b0 = (double)Wb[kb * 4];
                        double a1 = Arow[(kb + 1) * 4 + kq];
                        double b1 = (double)Wb[(kb + 1) * 4];
                        ax0 = __builtin_amdgcn_mfma_f64_16x16x4f64(a0, b0, ax0, 0, 0, 0);
                        ax1 = __builtin_amdgcn_mfma_f64_16x16x4f64(a1, b1, ax1, 0, 0, 0);
                    }
#pragma unroll
                    for (int r = 0; r < 4; ++r)
                        xgm[r] = __fadd_rn((float)(ax0[r] + ax1[r]), biasv[r]);
                }
            } else {
                double a0 = 0.0, a1 = 0.0;
                const double* A0 = Ah + (2 * w + 0) * ASTRD;
                const double* A1 = Ah + (2 * w + 1) * ASTRD;
#pragma unroll 4
                for (int k = 0; k < EE; k += 4) {
                    float4 wf = *((const float4*)(WrowL + k));
                    const double w0 = wf.x, w1 = wf.y, w2 = wf.z, w3 = wf.w;
                    double2 q0, q1;
                    q0 = *((const double2*)(A0 + k)); q1 = *((const double2*)(A0 + k + 2));
                    a0 += q0.x * w0 + q0.y * w1 + q1.x * w2 + q1.y * w3;
                    q0 = *((const double2*)(A1 + k)); q1 = *((const double2*)(A1 + k + 2));
                    a1 += q0.x * w0 + q0.y * w1 + q1.x * w2 + q1.y * w3;
                }
                xgv[0] = __fadd_rn((float)a0, bias_c);   // f32(Sx)+b
                xgv[1] = __fadd_rn((float)a1, bias_c);
            }
        }

        // ---- wait for h(s-1) (R3 verbatim) ----
        if (s > 0 && tid == 0) {
            const int target = 16 * s;
            while (__hip_atomic_load(mycnt, __ATOMIC_RELAXED,
                                     __HIP_MEMORY_SCOPE_AGENT) < target) {
                __builtin_amdgcn_s_sleep(2);
                if (++guard > 100000000L) {
                    __hip_atomic_store(&flags[10], s, __ATOMIC_RELAXED,
                                       __HIP_MEMORY_SCOPE_AGENT);
                    break;
                }
            }
            __threadfence();                         // acquire
        }
        __syncthreads();

        // ---- stage h(s-1) as f64 (R3 verbatim) ----
        if (s == 0) {
            for (int i = tid; i < 2048; i += 512) {
                int r = i >> 7, u2 = i & 127;
                *((double2*)(Ah + r * ASTRD + EE + u2 * 2)) = make_double2(0.0, 0.0);
            }
        } else {
            const int rp = (s & 1) ^ 1;
            int i = tid;
#pragma unroll
            for (int rep = 0; rep < 4; ++rep, i += 512) {
                int r = i >> 7, u2 = i & 127;
                const unsigned long long* p = (const unsigned long long*)
                    (hx + ((size_t)((rp * 2 + dir) * BB + b0 + r)) * HH + u2 * 2);
                unsigned long long raw = __hip_atomic_load(
                    p, __ATOMIC_RELAXED, __HIP_MEMORY_SCOPE_AGENT);
                union { unsigned long long u; float f[2]; } cv; cv.u = raw;
                *((double2*)(Ah + r * ASTRD + EE + u2 * 2)) =
                    make_double2((double)cv.f[0], (double)cv.f[1]);
            }
        }
        __syncthreads();

        // ---- emissions partial for step s-1 (threads 0-255, R3 verbatim) ----
        if (s >= 1 && tid < 256) {
            const int d = tid >> 3, sub = tid & 7;
            const int row = d >> 1, kk = d & 1;
            const int t_em = dir ? (TT - s) : (s - 1);
            double p = 0.0;
#pragma unroll
            for (int j = sub * 32; j < sub * 32 + 32; ++j)
                p += Ah[row * ASTRD + EE + j] * (double)Lw[kk * 256 + j];
            p += __shfl_xor(p, 1, 64);
            p += __shfl_xor(p, 2, 64);
            p += __shfl_xor(p, 4, 64);
            if (sub == 0)
                atomicAdd(em + ((size_t)(b0 + row) * TT + t_em) * KK + hsl * 2 + kk, p);
        }
        if (s == TT) break;

        // ---- h-phase GEMM; g = xg + f32(Sh) -> Gl ----
        if (mode != 0) {
            if (w < 4) {
                f64x4 ah0; ah0[0]=0.0; ah0[1]=0.0; ah0[2]=0.0; ah0[3]=0.0;
                f64x4 ah1 = ah0;
#pragma unroll 8
                for (int kb = 32; kb < 96; kb += 2) {
                    double a0 = Arow[kb * 4 + kq];
                    double b0 = (double)Wb[kb * 4];
                    double a1 = Arow[(kb + 1) * 4 + kq];
                    double b1 = (double)Wb[(kb + 1) * 4];
                    ah0 = __builtin_amdgcn_mfma_f64_16x16x4f64(a0, b0, ah0, 0, 0, 0);
                    ah1 = __builtin_amdgcn_mfma_f64_16x16x4f64(a1, b1, ah1, 0, 0, 0);
                }
#pragma unroll
                for (int r = 0; r < 4; ++r)
                    Gl[glIdx[r]] = __fadd_rn(xgm[r], (float)(ah0[r] + ah1[r]));
            }
        } else {
            double a0 = 0.0, a1 = 0.0;
            const double* A0 = Ah + (2 * w + 0) * ASTRD + EE;
            const double* A1 = Ah + (2 * w + 1) * ASTRD + EE;
            const float* WhL = WrowL + EE;
#pragma unroll 4
            for (int k = 0; k < HH; k += 4) {
                float4 wf = *((const float4*)(WhL + k));
                const double w0 = wf.x, w1 = wf.y, w2 = wf.z, w3 = wf.w;
                double2 q0, q1;
                q0 = *((const double2*)(A0 + k)); q1 = *((const double2*)(A0 + k + 2));
                a0 += q0.x * w0 + q0.y * w1 + q1.x * w2 + q1.y * w3;
                q0 = *((const double2*)(A1 + k)); q1 = *((const double2*)(A1 + k + 2));
                a1 += q0.x * w0 + q0.y * w1 + q1.x * w2 + q1.y * w3;
            }
            Gl[(2 * w + 0) * 66 + c] = __fadd_rn(xgv[0], (float)a0);
            Gl[(2 * w + 1) * 66 + c] = __fadd_rn(xgv[1], (float)a1);
        }
        __syncthreads();

        // ---- LSTM cell (f32 lattice, R3 verbatim; threads 0-255) ----
        if (tid < 256) {
            const float gi = Gl[er * 66 +  0 + eu];
            const float gf = Gl[er * 66 + 16 + eu];
            const float gg = Gl[er * 66 + 32 + eu];
            const float go = Gl[er * 66 + 48 + eu];
            const float si = 1.f / (1.f + expf(-gi));
            const float sf = 1.f / (1.f + expf(-gf));
            const float so = 1.f / (1.f + expf(-go));
            const float tg = tanhf(gg);
            const float cnew = __fadd_rn(__fmul_rn(sf, c_state), __fmul_rn(si, tg));
            c_state = cnew;
            const float hval = __fmul_rn(so, tanhf(cnew));
            __hip_atomic_store(
                hx + ((size_t)(((s & 1) * 2 + dir) * BB + b0 + er)) * HH + u0 + eu,
                hval, __ATOMIC_RELAXED, __HIP_MEMORY_SCOPE_AGENT);
        }

        // ---- signal h(s) ready (R3 verbatim) ----
        __syncthreads();     // drains all waves' h stores (vmcnt(0))
        if (tid == 0) {
            __threadfence();                         // release
            __hip_atomic_fetch_add(mycnt, 1, __ATOMIC_RELAXED,
                                   __HIP_MEMORY_SCOPE_AGENT);
        }
    }
}

// ---------------------------------------------------------------------------
// k_viterbi: f32 DP, reference rounding/order (PASSED verbatim).
// ---------------------------------------------------------------------------
__global__ __launch_bounds__(64) void k_viterbi(const double* __restrict__ em,
                                                const float* __restrict__ lb,
                                                const float* __restrict__ startt,
                                                const float* __restrict__ endt,
                                                const float* __restrict__ trans,
                                                int* __restrict__ out) {
    const int b = blockIdx.x;
    const int lane = threadIdx.x;
    const int j = lane & 31, half = lane >> 5;
    __shared__ float trs[32][33];
    __shared__ unsigned char hist[TT][32];
    __shared__ int tags[TT];

    for (int idx = lane; idx < 1024; idx += 64)
        trs[idx >> 5][idx & 31] = trans[idx];
    __syncthreads();

    const float lbj = lb[j];
    const double* emb = em + (size_t)b * TT * KK;
    float score = __fadd_rn(startt[j], __fadd_rn((float)emb[j], lbj));

    for (int t = 1; t < TT; ++t) {
        const float e_cur = __fadd_rn((float)emb[(size_t)t * KK + j], lbj);
        float best = -3.4e38f; int bi = 0;
#pragma unroll
        for (int ii = 0; ii < 16; ++ii) {
            int i = half * 16 + ii;
            float sc_i = __shfl(score, i, 64);
            float c1 = __fadd_rn(sc_i, trs[i][j]);
            float cand = __fadd_rn(c1, e_cur);
            if (cand > best) { best = cand; bi = i; }    // strict > = first max
        }
        float ob = __shfl_xor(best, 32, 64);
        int obi = __shfl_xor(bi, 32, 64);
        if (ob > best || (ob == best && obi < bi)) { best = ob; bi = obi; }
        score = best;
        if (half == 0) hist[t][j] = (unsigned char)bi;
    }

    score = __fadd_rn(score, endt[j]);
    int bj = j; float bs = score;
#pragma unroll
    for (int off = 16; off >= 1; off >>= 1) {
        float os = __shfl_xor(bs, off, 64);
        int oj = __shfl_xor(bj, off, 64);
        if (os > bs || (os == bs && oj < bj)) { bs = os; bj = oj; }
    }
    __syncthreads();
    if (lane == 0) {
        int cur = bj;
        tags[TT - 1] = cur;
        for (int t = TT - 2; t >= 0; --t) { cur = hist[t + 1][cur]; tags[t] = cur; }
    }
    __syncthreads();
    for (int t2 = lane; t2 < TT; t2 += 64) out[b * TT + t2] = tags[t2];
}

// ---------------------------------------------------------------------------
// k_final: failure decode only (healthy runs untouched).
// ---------------------------------------------------------------------------
__global__ __launch_bounds__(64) void k_final(const int* __restrict__ flags,
                                              int* __restrict__ outp) {
    if (threadIdx.x != 0) return;
    if (flags[8] != MAGIC)   outp[0] = 990000;
    else if (flags[10] != 0) outp[0] = 850000 + flags[10] * 64;
}

// ---------------------------------------------------------------------------
extern "C" void kernel_launch(void* const* d_in, const int* in_sizes, int n_in,
                              void* d_out, int out_size, void* d_ws, size_t ws_size,
                              hipStream_t stream) {
    const int*   tok   = (const int*)d_in[0];
    const float* table = (const float*)d_in[3];
    const float* Wihf  = (const float*)d_in[4];
    const float* Whhf  = (const float*)d_in[5];
    const float* bf    = (const float*)d_in[6];
    const float* Wihb  = (const float*)d_in[7];
    const float* Whhb  = (const float*)d_in[8];
    const float* bb    = (const float*)d_in[9];
    const float* lw    = (const float*)d_in[10];
    const float* lb    = (const float*)d_in[11];
    const float* st    = (const float*)d_in[12];
    const float* en    = (const float*)d_in[13];
    const float* tr    = (const float*)d_in[14];

    if (ws_size < (19ull << 20)) return;

    char* ws = (char*)d_ws;
    float*  hx    = (float*)ws;
    int*    cnt   = (int*)(ws + OFF_CNT);
    int*    flags = (int*)(ws + OFF_FLG);
    double* em    = (double*)(ws + OFF_EM);

    hipMemsetAsync(cnt, 0, 8192, stream);            // cnt + flags
    hipMemsetAsync(em, 0, (size_t)BB * TT * KK * 8, stream);
    k_persist<<<256, 512, 0, stream>>>(tok, table, Wihf, Whhf, bf,
                                       Wihb, Whhb, bb, lw, hx, cnt, em, flags);
    k_viterbi<<<BB, 64, 0, stream>>>(em, lb, st, en, tr, (int*)d_out);
    k_final  <<<1, 64, 0, stream>>>(flags, (int*)d_out);
}

// Round 12
// 6623.329 us; speedup vs baseline: 1.2452x; 1.2333x over previous
//
#include <hip/hip_runtime.h>
#include <stdint.h>

#define BB 128
#define TT 512
#define EE 128
#define HH 256
#define KK 32
#define ASTRD 386    // f64 stride of A-tile rows (384+2 pad)
#define WSTR  388    // f32 stride of W rows: %32==4, 16B aligned
#define MAGIC 0x13572468

typedef double f64x4 __attribute__((ext_vector_type(4)));

// Workspace: hx f32 [2par][2dir][B][H] @0 (512 KB); cnt @512K; flags @516K;
//            em f64 [B][T][K] @2M (16 MB).
#define OFF_CNT (512ull << 10)
#define OFF_FLG (516ull << 10)
#define OFF_EM  (2ull << 20)

// ---------------------------------------------------------------------------
// k_persist: R3 structure (PASSED 8247us; R6 re-run 8168us) + f64-MFMA GEMM
// behind a runtime layout DISCOVERY probe.
// R6 post-mortem: MfmaUtil 0.001 (probe-only) => both guessed D-layouts
// (canonical 16x16-family + transpose) are WRONG for v_mfma_f64_16x16x4f64.
// Discovery (register-only, exact integer-in-f64):
//   P1 a=l, b=1:  B==1 under ANY layout -> d = sum_k A[row][k] = lane-id sum
//      of row's lane group: 96+4*row (m-low: lane=m+16k) or 16*row+6
//      (k-low: lane=4m+k). Disjoint codebooks -> per-(lane,reg) D-row readout
//      (ground truth) + A-style.
//   P2 a=1, b=l:  symmetric -> D-col readout + B-style.
//   P3 a=k_label, b=2^k_label: d==34.0 everywhere iff A/B k-labelings pair
//      consistently (sum sigma(k)*2^k = 34 <=> sigma = id); a common
//      permutation on both sides only reorders exact-f64 summands (safe).
// All pass -> mode 1: per-thread rowIdx[]/colIdx[] register maps drive Gl
// writes + bias; else mode 0 = R3 scalar GEMM verbatim (bit-identical PASS).
// Staging/sync/em/cell/Viterbi: R3 verbatim. LDS 155 KB -> 1 block/CU.
// ---------------------------------------------------------------------------
__global__ __launch_bounds__(512, 1) void k_persist(
        const int* __restrict__ tok, const float* __restrict__ table,
        const float* __restrict__ Wihf, const float* __restrict__ Whhf,
        const float* __restrict__ bf,
        const float* __restrict__ Wihb, const float* __restrict__ Whhb,
        const float* __restrict__ bb,
        const float* __restrict__ lw,
        float* __restrict__ hx, int* __restrict__ cnt,
        double* __restrict__ em, int* __restrict__ flags) {
    __shared__ __align__(16) double Ah[16 * ASTRD];
    __shared__ __align__(16) float  Wl[64 * WSTR];
    __shared__ float Gl[16 * 66];
    __shared__ float Lw[2 * 256];

    const int tid  = threadIdx.x;
    const int blk  = blockIdx.x;
    const int grp  = blk & 15;
    const int dir  = grp >> 3;
    const int tile = grp & 7;
    const int hsl  = blk >> 4;
    const int b0   = tile * 16;
    const int u0   = hsl * 16;
    int* mycnt = cnt + grp * 64;

    if (blk == 0 && tid == 0) flags[8] = MAGIC;      // liveness

    const float* Wih = dir ? Wihb : Wihf;
    const float* Whh = dir ? Whhb : Whhf;
    const float* bia = dir ? bb : bf;

    // ---- one-time: W slice into LDS (row c = gate*16+unit, stride 388) ----
    for (int idx = tid; idx < 64 * 384; idx += 512) {
        int c = idx / 384;
        int k = idx - c * 384;
        int grow = (c >> 4) * HH + u0 + (c & 15);
        float v = (k < EE) ? Wih[(size_t)grow * EE + k]
                           : Whh[(size_t)grow * HH + (k - EE)];
        Wl[c * WSTR + k] = v;
    }
    {
        int i = tid;
        Lw[i] = lw[(size_t)(hsl * 2 + (i >> 8)) * (2 * HH) + dir * HH + (i & 255)];
    }

    const int l = tid & 63;
    const int w = tid >> 6;

    // ---- runtime MFMA layout DISCOVERY (register-only, exact) ----
    int mode = 0;
    int rowIdx[4] = {0, 0, 0, 0}, colIdx[4] = {0, 0, 0, 0};
    int mAi = l & 15, kAi = l >> 4, nBi = l & 15, kBi = l >> 4;
    {
        f64x4 z; z[0] = 0.0; z[1] = 0.0; z[2] = 0.0; z[3] = 0.0;
        f64x4 d1 = __builtin_amdgcn_mfma_f64_16x16x4f64((double)l, 1.0, z, 0, 0, 0);
        f64x4 d2 = __builtin_amdgcn_mfma_f64_16x16x4f64(1.0, (double)l, z, 0, 0, 0);
        bool am = true, ak = true, bm = true, bk = true;
        int rm[4], rk[4], cm[4], ck[4];
#pragma unroll
        for (int r = 0; r < 4; ++r) {
            const int v1 = (int)d1[r], v2 = (int)d2[r];
            const bool e1 = ((double)v1 == d1[r]);
            const bool e2 = ((double)v2 == d2[r]);
            rm[r] = (v1 - 96) >> 2;
            am = am && e1 && (((v1 - 96) & 3) == 0) && rm[r] >= 0 && rm[r] < 16;
            rk[r] = (v1 - 6) >> 4;
            ak = ak && e1 && (((v1 - 6) & 15) == 0) && rk[r] >= 0 && rk[r] < 16;
            cm[r] = (v2 - 96) >> 2;
            bm = bm && e2 && (((v2 - 96) & 3) == 0) && cm[r] >= 0 && cm[r] < 16;
            ck[r] = (v2 - 6) >> 4;
            bk = bk && e2 && (((v2 - 6) & 15) == 0) && ck[r] >= 0 && ck[r] < 16;
        }
        const bool Am = (__ballot(am ? 1 : 0) == ~0ull);
        const bool Ak = (__ballot(ak ? 1 : 0) == ~0ull);
        const bool Bm = (__ballot(bm ? 1 : 0) == ~0ull);
        const bool Bk = (__ballot(bk ? 1 : 0) == ~0ull);
        if ((Am || Ak) && (Bm || Bk)) {
            mAi = Am ? (l & 15) : (l >> 2);
            kAi = Am ? (l >> 4) : (l & 3);
            nBi = Bm ? (l & 15) : (l >> 2);
            kBi = Bm ? (l >> 4) : (l & 3);
            f64x4 d3 = __builtin_amdgcn_mfma_f64_16x16x4f64(
                (double)kAi, (double)(1 << kBi), z, 0, 0, 0);
            const bool k34 = (d3[0] == 34.0) && (d3[1] == 34.0) &&
                             (d3[2] == 34.0) && (d3[3] == 34.0);
            if (__ballot(k34 ? 1 : 0) == ~0ull) {
                mode = 1;
#pragma unroll
                for (int r = 0; r < 4; ++r) {
                    rowIdx[r] = Am ? rm[r] : rk[r];
                    colIdx[r] = Bm ? cm[r] : ck[r];
                }
            }
        }
    }

    // ---- scalar-path mapping (R3 verbatim) ----
    const int c = tid & 63;
    const float* WrowL = Wl + c * WSTR;
    const float bias_c = bia[(c >> 4) * HH + u0 + (c & 15)];

    // ---- MFMA-path mapping (waves 0-3, gate g = w) ----
    const double* Arow = Ah + mAi * ASTRD;
    const float*  Wb   = Wl + (w * 16 + nBi) * WSTR + kBi;
    int   glIdx[4];
    float biasv[4];
#pragma unroll
    for (int r = 0; r < 4; ++r) {
        glIdx[r] = rowIdx[r] * 66 + w * 16 + colIdx[r];
        biasv[r] = bia[w * HH + u0 + colIdx[r]];
    }

    const int er = tid >> 4, eu = tid & 15;          // cell mapping (tid<256)
    float c_state = 0.f;
    long guard = 0;
    float xgv[2];
    float xgm[4];

    for (int s = 0; s <= TT; ++s) {
        // ---- stage x(t_s) as f64 (h-independent); 512 float4, 1/thread ----
        if (s < TT) {
            const int t = dir ? (TT - 1 - s) : s;
            const int i = tid;
            const int r = i >> 5, e4 = i & 31;
            int tk = tok[(b0 + r) * TT + t];
            float4 v = make_float4(0.f, 0.f, 0.f, 0.f);
            if (tk != 0) v = ((const float4*)(table + (size_t)tk * EE))[e4];
            double2* dst = (double2*)(Ah + r * ASTRD + e4 * 4);
            dst[0] = make_double2((double)v.x, (double)v.y);
            dst[1] = make_double2((double)v.z, (double)v.w);
        }
        __syncthreads();

        // ---- x-phase GEMM (before barrier wait; hides inter-block skew) ----
        if (s < TT) {
            if (mode != 0) {
                if (w < 4) {
                    f64x4 ax0; ax0[0]=0.0; ax0[1]=0.0; ax0[2]=0.0; ax0[3]=0.0;
                    f64x4 ax1 = ax0;
#pragma unroll 8
                    for (int kb = 0; kb < 32; kb += 2) {
                        double a0 = Arow[kb * 4 + kAi];
                        double b0 = (double)Wb[kb * 4];
                        double a1 = Arow[(kb + 1) * 4 + kAi];
                        double b1 = (double)Wb[(kb + 1) * 4];
                        ax0 = __builtin_amdgcn_mfma_f64_16x16x4f64(a0, b0, ax0, 0, 0, 0);
                        ax1 = __builtin_amdgcn_mfma_f64_16x16x4f64(a1, b1, ax1, 0, 0, 0);
                    }
#pragma unroll
                    for (int r = 0; r < 4; ++r)
                        xgm[r] = __fadd_rn((float)(ax0[r] + ax1[r]), biasv[r]);
                }
            } else {
                double a0 = 0.0, a1 = 0.0;
                const double* A0 = Ah + (2 * w + 0) * ASTRD;
                const double* A1 = Ah + (2 * w + 1) * ASTRD;
#pragma unroll 4
                for (int k = 0; k < EE; k += 4) {
                    float4 wf = *((const float4*)(WrowL + k));
                    const double w0 = wf.x, w1 = wf.y, w2 = wf.z, w3 = wf.w;
                    double2 q0, q1;
                    q0 = *((const double2*)(A0 + k)); q1 = *((const double2*)(A0 + k + 2));
                    a0 += q0.x * w0 + q0.y * w1 + q1.x * w2 + q1.y * w3;
                    q0 = *((const double2*)(A1 + k)); q1 = *((const double2*)(A1 + k + 2));
                    a1 += q0.x * w0 + q0.y * w1 + q1.x * w2 + q1.y * w3;
                }
                xgv[0] = __fadd_rn((float)a0, bias_c);   // f32(Sx)+b
                xgv[1] = __fadd_rn((float)a1, bias_c);
            }
        }

        // ---- wait for h(s-1) (R3 verbatim) ----
        if (s > 0 && tid == 0) {
            const int target = 16 * s;
            while (__hip_atomic_load(mycnt, __ATOMIC_RELAXED,
                                     __HIP_MEMORY_SCOPE_AGENT) < target) {
                __builtin_amdgcn_s_sleep(2);
                if (++guard > 100000000L) {
                    __hip_atomic_store(&flags[10], s, __ATOMIC_RELAXED,
                                       __HIP_MEMORY_SCOPE_AGENT);
                    break;
                }
            }
            __threadfence();                         // acquire
        }
        __syncthreads();

        // ---- stage h(s-1) as f64 (R3 verbatim) ----
        if (s == 0) {
            for (int i = tid; i < 2048; i += 512) {
                int r = i >> 7, u2 = i & 127;
                *((double2*)(Ah + r * ASTRD + EE + u2 * 2)) = make_double2(0.0, 0.0);
            }
        } else {
            const int rp = (s & 1) ^ 1;
            int i = tid;
#pragma unroll
            for (int rep = 0; rep < 4; ++rep, i += 512) {
                int r = i >> 7, u2 = i & 127;
                const unsigned long long* p = (const unsigned long long*)
                    (hx + ((size_t)((rp * 2 + dir) * BB + b0 + r)) * HH + u2 * 2);
                unsigned long long raw = __hip_atomic_load(
                    p, __ATOMIC_RELAXED, __HIP_MEMORY_SCOPE_AGENT);
                union { unsigned long long u; float f[2]; } cv; cv.u = raw;
                *((double2*)(Ah + r * ASTRD + EE + u2 * 2)) =
                    make_double2((double)cv.f[0], (double)cv.f[1]);
            }
        }
        __syncthreads();

        // ---- emissions partial for step s-1 (threads 0-255, R3 verbatim) ----
        if (s >= 1 && tid < 256) {
            const int d = tid >> 3, sub = tid & 7;
            const int row = d >> 1, kk = d & 1;
            const int t_em = dir ? (TT - s) : (s - 1);
            double p = 0.0;
#pragma unroll
            for (int j = sub * 32; j < sub * 32 + 32; ++j)
                p += Ah[row * ASTRD + EE + j] * (double)Lw[kk * 256 + j];
            p += __shfl_xor(p, 1, 64);
            p += __shfl_xor(p, 2, 64);
            p += __shfl_xor(p, 4, 64);
            if (sub == 0)
                atomicAdd(em + ((size_t)(b0 + row) * TT + t_em) * KK + hsl * 2 + kk, p);
        }
        if (s == TT) break;

        // ---- h-phase GEMM; g = xg + f32(Sh) -> Gl ----
        if (mode != 0) {
            if (w < 4) {
                f64x4 ah0; ah0[0]=0.0; ah0[1]=0.0; ah0[2]=0.0; ah0[3]=0.0;
                f64x4 ah1 = ah0;
#pragma unroll 8
                for (int kb = 32; kb < 96; kb += 2) {
                    double a0 = Arow[kb * 4 + kAi];
                    double b0 = (double)Wb[kb * 4];
                    double a1 = Arow[(kb + 1) * 4 + kAi];
                    double b1 = (double)Wb[(kb + 1) * 4];
                    ah0 = __builtin_amdgcn_mfma_f64_16x16x4f64(a0, b0, ah0, 0, 0, 0);
                    ah1 = __builtin_amdgcn_mfma_f64_16x16x4f64(a1, b1, ah1, 0, 0, 0);
                }
#pragma unroll
                for (int r = 0; r < 4; ++r)
                    Gl[glIdx[r]] = __fadd_rn(xgm[r], (float)(ah0[r] + ah1[r]));
            }
        } else {
            double a0 = 0.0, a1 = 0.0;
            const double* A0 = Ah + (2 * w + 0) * ASTRD + EE;
            const double* A1 = Ah + (2 * w + 1) * ASTRD + EE;
            const float* WhL = WrowL + EE;
#pragma unroll 4
            for (int k = 0; k < HH; k += 4) {
                float4 wf = *((const float4*)(WhL + k));
                const double w0 = wf.x, w1 = wf.y, w2 = wf.z, w3 = wf.w;
                double2 q0, q1;
                q0 = *((const double2*)(A0 + k)); q1 = *((const double2*)(A0 + k + 2));
                a0 += q0.x * w0 + q0.y * w1 + q1.x * w2 + q1.y * w3;
                q0 = *((const double2*)(A1 + k)); q1 = *((const double2*)(A1 + k + 2));
                a1 += q0.x * w0 + q0.y * w1 + q1.x * w2 + q1.y * w3;
            }
            Gl[(2 * w + 0) * 66 + c] = __fadd_rn(xgv[0], (float)a0);
            Gl[(2 * w + 1) * 66 + c] = __fadd_rn(xgv[1], (float)a1);
        }
        __syncthreads();

        // ---- LSTM cell (f32 lattice, R3 verbatim; threads 0-255) ----
        if (tid < 256) {
            const float gi = Gl[er * 66 +  0 + eu];
            const float gf = Gl[er * 66 + 16 + eu];
            const float gg = Gl[er * 66 + 32 + eu];
            const float go = Gl[er * 66 + 48 + eu];
            const float si = 1.f / (1.f + expf(-gi));
            const float sf = 1.f / (1.f + expf(-gf));
            const float so = 1.f / (1.f + expf(-go));
            const float tg = tanhf(gg);
            const float cnew = __fadd_rn(__fmul_rn(sf, c_state), __fmul_rn(si, tg));
            c_state = cnew;
            const float hval = __fmul_rn(so, tanhf(cnew));
            __hip_atomic_store(
                hx + ((size_t)(((s & 1) * 2 + dir) * BB + b0 + er)) * HH + u0 + eu,
                hval, __ATOMIC_RELAXED, __HIP_MEMORY_SCOPE_AGENT);
        }

        // ---- signal h(s) ready (R3 verbatim) ----
        __syncthreads();     // drains all waves' h stores (vmcnt(0))
        if (tid == 0) {
            __threadfence();                         // release
            __hip_atomic_fetch_add(mycnt, 1, __ATOMIC_RELAXED,
                                   __HIP_MEMORY_SCOPE_AGENT);
        }
    }
}

// ---------------------------------------------------------------------------
// k_viterbi: f32 DP, reference rounding/order (PASSED verbatim).
// ---------------------------------------------------------------------------
__global__ __launch_bounds__(64) void k_viterbi(const double* __restrict__ em,
                                                const float* __restrict__ lb,
                                                const float* __restrict__ startt,
                                                const float* __restrict__ endt,
                                                const float* __restrict__ trans,
                                                int* __restrict__ out) {
    const int b = blockIdx.x;
    const int lane = threadIdx.x;
    const int j = lane & 31, half = lane >> 5;
    __shared__ float trs[32][33];
    __shared__ unsigned char hist[TT][32];
    __shared__ int tags[TT];

    for (int idx = lane; idx < 1024; idx += 64)
        trs[idx >> 5][idx & 31] = trans[idx];
    __syncthreads();

    const float lbj = lb[j];
    const double* emb = em + (size_t)b * TT * KK;
    float score = __fadd_rn(startt[j], __fadd_rn((float)emb[j], lbj));

    for (int t = 1; t < TT; ++t) {
        const float e_cur = __fadd_rn((float)emb[(size_t)t * KK + j], lbj);
        float best = -3.4e38f; int bi = 0;
#pragma unroll
        for (int ii = 0; ii < 16; ++ii) {
            int i = half * 16 + ii;
            float sc_i = __shfl(score, i, 64);
            float c1 = __fadd_rn(sc_i, trs[i][j]);
            float cand = __fadd_rn(c1, e_cur);
            if (cand > best) { best = cand; bi = i; }    // strict > = first max
        }
        float ob = __shfl_xor(best, 32, 64);
        int obi = __shfl_xor(bi, 32, 64);
        if (ob > best || (ob == best && obi < bi)) { best = ob; bi = obi; }
        score = best;
        if (half == 0) hist[t][j] = (unsigned char)bi;
    }

    score = __fadd_rn(score, endt[j]);
    int bj = j; float bs = score;
#pragma unroll
    for (int off = 16; off >= 1; off >>= 1) {
        float os = __shfl_xor(bs, off, 64);
        int oj = __shfl_xor(bj, off, 64);
        if (os > bs || (os == bs && oj < bj)) { bs = os; bj = oj; }
    }
    __syncthreads();
    if (lane == 0) {
        int cur = bj;
        tags[TT - 1] = cur;
        for (int t = TT - 2; t >= 0; --t) { cur = hist[t + 1][cur]; tags[t] = cur; }
    }
    __syncthreads();
    for (int t2 = lane; t2 < TT; t2 += 64) out[b * TT + t2] = tags[t2];
}

// ---------------------------------------------------------------------------
// k_final: failure decode only (healthy runs untouched).
// ---------------------------------------------------------------------------
__global__ __launch_bounds__(64) void k_final(const int* __restrict__ flags,
                                              int* __restrict__ outp) {
    if (threadIdx.x != 0) return;
    if (flags[8] != MAGIC)   outp[0] = 990000;
    else if (flags[10] != 0) outp[0] = 850000 + flags[10] * 64;
}

// ---------------------------------------------------------------------------
extern "C" void kernel_launch(void* const* d_in, const int* in_sizes, int n_in,
                              void* d_out, int out_size, void* d_ws, size_t ws_size,
                              hipStream_t stream) {
    const int*   tok   = (const int*)d_in[0];
    const float* table = (const float*)d_in[3];
    const float* Wihf  = (const float*)d_in[4];
    const float* Whhf  = (const float*)d_in[5];
    const float* bf    = (const float*)d_in[6];
    const float* Wihb  = (const float*)d_in[7];
    const float* Whhb  = (const float*)d_in[8];
    const float* bb    = (const float*)d_in[9];
    const float* lw    = (const float*)d_in[10];
    const float* lb    = (const float*)d_in[11];
    const float* st    = (const float*)d_in[12];
    const float* en    = (const float*)d_in[13];
    const float* tr    = (const float*)d_in[14];

    if (ws_size < (19ull << 20)) return;

    char* ws = (char*)d_ws;
    float*  hx    = (float*)ws;
    int*    cnt   = (int*)(ws + OFF_CNT);
    int*    flags = (int*)(ws + OFF_FLG);
    double* em    = (double*)(ws + OFF_EM);

    hipMemsetAsync(cnt, 0, 8192, stream);            // cnt + flags
    hipMemsetAsync(em, 0, (size_t)BB * TT * KK * 8, stream);
    k_persist<<<256, 512, 0, stream>>>(tok, table, Wihf, Whhf, bf,
                                       Wihb, Whhb, bb, lw, hx, cnt, em, flags);
    k_viterbi<<<BB, 64, 0, stream>>>(em, lb, st, en, tr, (int*)d_out);
    k_final  <<<1, 64, 0, stream>>>(flags, (int*)d_out);
}